// Round 4
// baseline (609.623 us; speedup 1.0000x reference)
//
#include <hip/hip_runtime.h>

typedef __attribute__((ext_vector_type(8))) short short8;
typedef __attribute__((ext_vector_type(4))) float floatx4;

__device__ __forceinline__ unsigned short f2bf(float f) {
    unsigned int u = __float_as_uint(f);
    u += 0x7FFFu + ((u >> 16) & 1u);   // round-to-nearest-even
    return (unsigned short)(u >> 16);
}
__device__ __forceinline__ float bf2f(unsigned short h) {
    return __uint_as_float(((unsigned int)h) << 16);
}

// W[k][n] fp32 -> Wt bf16 in MFMA-B fragment order (frag id = (tl*8+ks)*64+lane),
// elems W[k0..k0+7][n], n = tl*16+(lane&15), k0 = ks*32+(lane>>4)*8.
// Also zeros num[16384].
__global__ __launch_bounds__(256) void k_wt(const float* __restrict__ W,
                                            unsigned short* __restrict__ Wt,
                                            float* __restrict__ num) {
    const int t = threadIdx.x;
    const int fid = (blockIdx.x << 8) + t;          // 0..8191
    ((float2*)num)[fid] = float2{0.f, 0.f};
    const int lane = fid & 63;
    const int tks = fid >> 6;
    const int tl = tks >> 3, ks = tks & 7;
    const int n  = (tl << 4) + (lane & 15);
    const int k0 = (ks << 5) + ((lane >> 4) << 3);
    short8 v;
#pragma unroll
    for (int i = 0; i < 8; ++i) v[i] = (short)f2bf(W[(k0 + i) * 256 + n]);
    *(short8*)(Wt + (size_t)fid * 8) = v;
}

// 256 blocks x 512 threads. Block owns 512 rows (4 chunks x 128; wave: 16 rows/chunk).
// W resident in LDS (staged once). Barrier-free main loop, reg-prefetch of next x chunk.
// Numerator accumulated in-register from afrag -> x read from HBM exactly once.
__global__ __launch_bounds__(512, 2) void k_main(
        const float* __restrict__ x, const unsigned short* __restrict__ Wt,
        const float* __restrict__ bias, const float* __restrict__ u,
        float* __restrict__ ea_all, float* __restrict__ num) {
    __shared__ __align__(16) unsigned char wlds[131072];
    __shared__ float num_lds[256];
    const int tid = threadIdx.x;
    const int lane = tid & 63;
    const int wv = tid >> 6;
    const int rl = lane & 15;          // row within m-tile / col within n-tile
    const int g  = lane >> 4;          // quad group
    const int m0 = blockIdx.x << 9;    // 512 rows per block
    const int batch = blockIdx.x >> 2; // 4 blocks per batch row-range (2048)

    if (tid < 256) num_lds[tid] = 0.f;

    // ---- prefetch chunk 0 (this wave's 16 rows, full K=256) ----
    const float* xw = x + (size_t)(m0 + (wv << 4) + rl) * 256 + (g << 3);
    float4 pf[16];
#pragma unroll
    for (int ks = 0; ks < 8; ++ks) {
        pf[2 * ks]     = *(const float4*)(xw + ks * 32);
        pf[2 * ks + 1] = *(const float4*)(xw + ks * 32 + 4);
    }
    // ---- stage W -> LDS once (identity copy, fragment-linear, coalesced) ----
#pragma unroll
    for (int i = 0; i < 16; ++i) {
        const int off = (i << 9) + tid;   // 16B units
        *(short8*)(wlds + (off << 4)) =
            *(const short8*)((const unsigned char*)Wt + (off << 4));
    }
    __syncthreads();

    float num_acc[64];
#pragma unroll
    for (int i = 0; i < 64; ++i) num_acc[i] = 0.f;

    for (int c = 0; c < 4; ++c) {
        // convert chunk-c x (waits on pf loads) -> A fragments
        short8 afrag[8];
#pragma unroll
        for (int ks = 0; ks < 8; ++ks) {
            const float4 v0 = pf[2 * ks], v1 = pf[2 * ks + 1];
            short8 a;
            a[0] = (short)f2bf(v0.x); a[1] = (short)f2bf(v0.y);
            a[2] = (short)f2bf(v0.z); a[3] = (short)f2bf(v0.w);
            a[4] = (short)f2bf(v1.x); a[5] = (short)f2bf(v1.y);
            a[6] = (short)f2bf(v1.z); a[7] = (short)f2bf(v1.w);
            afrag[ks] = a;
        }
        // prefetch chunk c+1 (stays in flight during MFMA below)
        if (c < 3) {
            const float* xn = xw + (size_t)(c + 1) * 128 * 256;
#pragma unroll
            for (int ks = 0; ks < 8; ++ks) {
                pf[2 * ks]     = *(const float4*)(xn + ks * 32);
                pf[2 * ks + 1] = *(const float4*)(xn + ks * 32 + 4);
            }
        }
        // GEMM over full N in two halves (acc pressure), B from LDS
        float p4[4] = {0.f, 0.f, 0.f, 0.f};
#pragma unroll
        for (int h = 0; h < 2; ++h) {
            floatx4 acc[8];
#pragma unroll
            for (int e = 0; e < 8; ++e) acc[e] = floatx4{0.f, 0.f, 0.f, 0.f};
#pragma unroll
            for (int ks = 0; ks < 8; ++ks) {
#pragma unroll
                for (int e = 0; e < 8; ++e) {
                    const int tl = (h << 3) + e;
                    const short8 b = *(const short8*)(
                        wlds + (((((tl << 3) + ks) << 6) + lane) << 4));
                    acc[e] = __builtin_amdgcn_mfma_f32_16x16x32_bf16(
                        afrag[ks], b, acc[e], 0, 0, 0);
                }
            }
            // tanh + partial dot(u); C/D layout: col=lane&15, row=(lane>>4)*4+j
#pragma unroll
            for (int e = 0; e < 8; ++e) {
                const int tl = (h << 3) + e;
                const int col = (tl << 4) + rl;
                const float uu = u[col];
                const float bb = bias[col];
#pragma unroll
                for (int j = 0; j < 4; ++j) {
                    const float v = acc[e][j] + bb;
                    const float ex = __expf(2.0f * v);
                    const float th = 1.0f - 2.0f * __builtin_amdgcn_rcpf(ex + 1.0f);
                    p4[j] += th * uu;
                }
            }
        }
        // reduce over 16 col-lanes -> ait, then ea for rows g*4+j
#pragma unroll
        for (int j = 0; j < 4; ++j) {
            float s = p4[j];
            s += __shfl_xor(s, 1); s += __shfl_xor(s, 2);
            s += __shfl_xor(s, 4); s += __shfl_xor(s, 8);
            p4[j] = __expf(s);
        }
        const int rowbase = m0 + (c << 7) + (wv << 4);
        if (rl == 0) {
#pragma unroll
            for (int j = 0; j < 4; ++j) ea_all[rowbase + (g << 2) + j] = p4[j];
        }
        // own-row ea via shfl transpose: row r lives as p4[r&3] on group r>>2
        const int idx = rl & 3;
        float esel = p4[0];
        esel = (idx == 1) ? p4[1] : esel;
        esel = (idx == 2) ? p4[2] : esel;
        esel = (idx == 3) ? p4[3] : esel;
        const float me = __shfl(esel, ((rl >> 2) << 4) | rl);
        // accumulate numerator: own row rl, f = ks*32 + g*8 + jj
#pragma unroll
        for (int ks = 0; ks < 8; ++ks) {
#pragma unroll
            for (int jj = 0; jj < 8; ++jj)
                num_acc[ks * 8 + jj] = fmaf(bf2f((unsigned short)afrag[ks][jj]), me,
                                            num_acc[ks * 8 + jj]);
        }
    }

    // reduce numerator over the 16 row-lanes, combine in LDS, one atomic per col
#pragma unroll
    for (int i = 0; i < 64; ++i) {
        float s = num_acc[i];
        s += __shfl_xor(s, 1); s += __shfl_xor(s, 2);
        s += __shfl_xor(s, 4); s += __shfl_xor(s, 8);
        num_acc[i] = s;
    }
    if (rl == 0) {
#pragma unroll
        for (int ks = 0; ks < 8; ++ks) {
#pragma unroll
            for (int jj = 0; jj < 8; ++jj)
                atomicAdd(&num_lds[(ks << 5) + (g << 3) + jj], num_acc[ks * 8 + jj]);
        }
    }
    __syncthreads();
    if (tid < 256) atomicAdd(&num[(batch << 8) + tid], num_lds[tid]);
}

// denom per batch + finalize
__global__ __launch_bounds__(256) void k_final(const float* __restrict__ ea_all,
                                               const float* __restrict__ num,
                                               float* __restrict__ out) {
    __shared__ float red[8];
    const int b = blockIdx.x, tid = threadIdx.x;
    float s = 0.f;
#pragma unroll
    for (int i = 0; i < 8; ++i) s += ea_all[(b << 11) + (i << 8) + tid];
    s += __shfl_xor(s, 1);  s += __shfl_xor(s, 2);  s += __shfl_xor(s, 4);
    s += __shfl_xor(s, 8);  s += __shfl_xor(s, 16); s += __shfl_xor(s, 32);
    if ((tid & 63) == 0) red[tid >> 6] = s;
    __syncthreads();
    if (tid == 0) red[4] = 1.0f / (red[0] + red[1] + red[2] + red[3] + 1e-7f);
    __syncthreads();
    out[(b << 8) + tid] = num[(b << 8) + tid] * red[4];
}

extern "C" void kernel_launch(void* const* d_in, const int* in_sizes, int n_in,
                              void* d_out, int out_size, void* d_ws, size_t ws_size,
                              hipStream_t stream) {
    const float* x    = (const float*)d_in[0];
    const float* W    = (const float*)d_in[1];
    const float* bias = (const float*)d_in[2];
    const float* u    = (const float*)d_in[3];
    float* out = (float*)d_out;
    unsigned char* ws = (unsigned char*)d_ws;
    unsigned short* Wt = (unsigned short*)(ws);            // 131072 B (fragment order)
    float* ea_all      = (float*)(ws + 131072);            // 524288 B
    float* num         = (float*)(ws + 131072 + 524288);   // 65536 B

    k_wt<<<32, 256, 0, stream>>>(W, Wt, num);
    k_main<<<256, 512, 0, stream>>>(x, Wt, bias, u, ea_all, num);
    k_final<<<64, 256, 0, stream>>>(ea_all, num, out);
}

// Round 6
// 217.198 us; speedup vs baseline: 2.8068x; 2.8068x over previous
//
#include <hip/hip_runtime.h>

typedef __attribute__((ext_vector_type(8))) short short8;
typedef __attribute__((ext_vector_type(4))) float floatx4;

#define EA_OFF  32768                 // x tile: [0, 32768)
#define W_OFF   33792                 // two 8 KB W buffers, 1 KB-aligned
#define LDS_TOTAL (33792 + 16384)

__device__ __forceinline__ unsigned short f2bf(float f) {
    unsigned int u = __float_as_uint(f);
    u += 0x7FFFu + ((u >> 16) & 1u);   // round-to-nearest-even
    return (unsigned short)(u >> 16);
}
__device__ __forceinline__ float bf2f(unsigned short h) {
    return __uint_as_float(((unsigned int)h) << 16);
}
__device__ __forceinline__ void gload16(const void* g, void* l) {
    __builtin_amdgcn_global_load_lds(
        (const __attribute__((address_space(1))) void*)g,
        (__attribute__((address_space(3))) void*)l, 16, 0, 0);
}

// W[k][n] fp32 -> Wt bf16 in MFMA-B fragment order (frag id = (tl*8+ks)*64+lane),
// elems W[k0..k0+7][n], n = tl*16+(lane&15), k0 = ks*32+(lane>>4)*8.
// Also zeros num[16384].
__global__ __launch_bounds__(256) void k_wt(const float* __restrict__ W,
                                            unsigned short* __restrict__ Wt,
                                            float* __restrict__ num) {
    const int t = threadIdx.x;
    const int fid = (blockIdx.x << 8) + t;          // 0..8191
    ((float2*)num)[fid] = float2{0.f, 0.f};
    const int lane = fid & 63;
    const int tks = fid >> 6;
    const int tl = tks >> 3, ks = tks & 7;
    const int n  = (tl << 4) + (lane & 15);
    const int k0 = (ks << 5) + ((lane >> 4) << 3);
    short8 v;
#pragma unroll
    for (int i = 0; i < 8; ++i) v[i] = (short)f2bf(W[(k0 + i) * 256 + n]);
    *(short8*)(Wt + (size_t)fid * 8) = v;
}

// 2048 blocks x 256 threads (4 waves). Block owns 64 rows; wave wv owns rows wv*16..+15
// across ALL 16 n-tiles. x staged once to LDS (bf16, XOR-swizzled). W double-buffered
// 8 KB tiles via async global_load_lds, issue-before-compute, 1 barrier/tile.
__global__ __launch_bounds__(256, 3) void k_main(
        const float* __restrict__ x, const unsigned short* __restrict__ Wt,
        const float* __restrict__ bias, const float* __restrict__ u,
        float* __restrict__ ea_all, float* __restrict__ num) {
    __shared__ __align__(16) unsigned char lds[LDS_TOTAL];
    const int tid = threadIdx.x;
    const int lane = tid & 63;
    const int wv = tid >> 6;
    const int rl = lane & 15;
    const int g  = lane >> 4;
    const int m0 = blockIdx.x << 6;     // 64 rows/block
    const int batch = blockIdx.x >> 5;  // 32 blocks per batch

    // ---- issue W tile-0 stage first (async, lands during x staging) ----
    {
        const unsigned char* wsrc = (const unsigned char*)Wt + (wv << 11) + (lane << 4);
        unsigned char* wdst = lds + W_OFF + (wv << 11);    // wave-uniform base
        gload16(wsrc, wdst);
        gload16(wsrc + 1024, wdst + 1024);
    }

    // ---- stage x: fp32 -> bf16, XOR-swizzled rows of 512 B ----
    {
        const int rr = tid >> 5;           // 8 rows per pass
        const int kf = (tid & 31) << 3;    // 8 floats/thread, coalesced
#pragma unroll
        for (int p = 0; p < 8; ++p) {
            const int r = (p << 3) + rr;
            const float* src = x + (size_t)(m0 + r) * 256 + kf;
            const float4 v0 = *(const float4*)(src);
            const float4 v1 = *(const float4*)(src + 4);
            short8 pk;
            pk[0] = (short)f2bf(v0.x); pk[1] = (short)f2bf(v0.y);
            pk[2] = (short)f2bf(v0.z); pk[3] = (short)f2bf(v0.w);
            pk[4] = (short)f2bf(v1.x); pk[5] = (short)f2bf(v1.y);
            pk[6] = (short)f2bf(v1.z); pk[7] = (short)f2bf(v1.w);
            *(short8*)(lds + ((r << 9) + ((kf << 1) ^ ((r & 7) << 4)))) = pk;
        }
    }

    // ---- preload u, bias for this lane's col in every n-tile ----
    float upre[16], bpre[16];
#pragma unroll
    for (int t = 0; t < 16; ++t) {
        const int col = (t << 4) + rl;
        upre[t] = u[col];
        bpre[t] = bias[col];
    }

    __syncthreads();   // x staged + W tile0 landed (implicit vmcnt/lgkm drain)

    // ---- A fragments for this wave's 16 rows (kept in regs) ----
    short8 afrag[8];
    {
        const int row = (wv << 4) + rl;
        const int abase = row << 9, aswz = (row & 7) << 4;
#pragma unroll
        for (int ks = 0; ks < 8; ++ks)
            afrag[ks] = *(const short8*)(lds + abase + (((ks << 6) + (g << 4)) ^ aswz));
    }

    // ---- N-loop: 16 tiles, double-buffered W, issue-before-compute ----
    float p4[4] = {0.f, 0.f, 0.f, 0.f};
    int cur = 0;
#pragma unroll
    for (int t = 0; t < 16; ++t) {
        if (t < 15) {
            const unsigned char* wsrc = (const unsigned char*)Wt + ((t + 1) << 13)
                                        + (wv << 11) + (lane << 4);
            unsigned char* wdst = lds + W_OFF + ((cur ^ 1) << 13) + (wv << 11);
            gload16(wsrc, wdst);
            gload16(wsrc + 1024, wdst + 1024);
        }
        floatx4 acc = floatx4{0.f, 0.f, 0.f, 0.f};
        const unsigned char* wb = lds + W_OFF + (cur << 13);
#pragma unroll
        for (int ks = 0; ks < 8; ++ks) {
            const short8 b = *(const short8*)(wb + (((ks << 6) + lane) << 4));
            acc = __builtin_amdgcn_mfma_f32_16x16x32_bf16(afrag[ks], b, acc, 0, 0, 0);
        }
        // tanh + dot(u) partial; C/D layout: col=lane&15, row=(lane>>4)*4+j
#pragma unroll
        for (int j = 0; j < 4; ++j) {
            const float v = acc[j] + bpre[t];
            const float ex = __expf(2.0f * v);
            const float th = 1.0f - 2.0f * __builtin_amdgcn_rcpf(ex + 1.0f);
            p4[j] = fmaf(th, upre[t], p4[j]);
        }
        __syncthreads();   // tile t reads done by all waves; t+1 loads landed
        cur ^= 1;
    }

    // ---- reduce over 16 col-lanes -> ait -> ea ----
#pragma unroll
    for (int j = 0; j < 4; ++j) {
        float s = p4[j];
        s += __shfl_xor(s, 1); s += __shfl_xor(s, 2);
        s += __shfl_xor(s, 4); s += __shfl_xor(s, 8);
        p4[j] = __expf(s);
    }
    float* ea_lds = (float*)(lds + EA_OFF);
    if (rl == 0) {
#pragma unroll
        for (int j = 0; j < 4; ++j) {
            const int r = (wv << 4) + (g << 2) + j;
            ea_lds[r] = p4[j];
            ea_all[m0 + r] = p4[j];
        }
    }
    __syncthreads();

    // ---- numerator: thread owns col tid; x read back from LDS (no 2nd HBM pass) ----
    {
        float s0 = 0.f;
        const int cb = tid << 1;
#pragma unroll 8
        for (int r = 0; r < 64; ++r) {
            const int a = (r << 9) + (cb ^ ((r & 7) << 4));
            s0 = fmaf(bf2f(*(const unsigned short*)(lds + a)), ea_lds[r], s0);
        }
        atomicAdd(&num[(batch << 8) + tid], s0);
    }
}

// denom per batch + finalize
__global__ __launch_bounds__(256) void k_final(const float* __restrict__ ea_all,
                                               const float* __restrict__ num,
                                               float* __restrict__ out) {
    __shared__ float red[8];
    const int b = blockIdx.x, tid = threadIdx.x;
    float s = 0.f;
#pragma unroll
    for (int i = 0; i < 8; ++i) s += ea_all[(b << 11) + (i << 8) + tid];
    s += __shfl_xor(s, 1);  s += __shfl_xor(s, 2);  s += __shfl_xor(s, 4);
    s += __shfl_xor(s, 8);  s += __shfl_xor(s, 16); s += __shfl_xor(s, 32);
    if ((tid & 63) == 0) red[tid >> 6] = s;
    __syncthreads();
    if (tid == 0) red[4] = 1.0f / (red[0] + red[1] + red[2] + red[3] + 1e-7f);
    __syncthreads();
    out[(b << 8) + tid] = num[(b << 8) + tid] * red[4];
}

extern "C" void kernel_launch(void* const* d_in, const int* in_sizes, int n_in,
                              void* d_out, int out_size, void* d_ws, size_t ws_size,
                              hipStream_t stream) {
    const float* x    = (const float*)d_in[0];
    const float* W    = (const float*)d_in[1];
    const float* bias = (const float*)d_in[2];
    const float* u    = (const float*)d_in[3];
    float* out = (float*)d_out;
    unsigned char* ws = (unsigned char*)d_ws;
    unsigned short* Wt = (unsigned short*)(ws);            // 131072 B (fragment order)
    float* ea_all      = (float*)(ws + 131072);            // 524288 B
    float* num         = (float*)(ws + 131072 + 524288);   // 65536 B

    k_wt<<<32, 256, 0, stream>>>(W, Wt, num);
    k_main<<<2048, 256, 0, stream>>>(x, Wt, bias, u, ea_all, num);
    k_final<<<64, 256, 0, stream>>>(ea_all, num, out);
}